// Round 2
// baseline (680.459 us; speedup 1.0000x reference)
//
#include <hip/hip_runtime.h>
#include <hip/hip_bf16.h>

#define DMODEL 1024
#define NH 16
#define HD 64
#define SEQ 2048
#define BATCH 2
#define BH (BATCH * NH)     // 32
#define MTOT (BATCH * SEQ)  // 4096

typedef __bf16 bf16x8 __attribute__((ext_vector_type(8)));
typedef float f32x4 __attribute__((ext_vector_type(4)));

// ---------------------------------------------------------------------------
// K1: QKV projection. X[4096,1024] @ W[1024,3072] + b -> Q,K,V bf16 [BH][SEQ][64]
// Q pre-scaled by 1/sqrt(HD) = 0.125.
// ---------------------------------------------------------------------------
__global__ __launch_bounds__(256) void qkv_gemm(const float* __restrict__ X,
                                                const float* __restrict__ W,
                                                const float* __restrict__ bias,
                                                __bf16* __restrict__ qb,
                                                __bf16* __restrict__ kb,
                                                __bf16* __restrict__ vb) {
  __shared__ __align__(16) float As[16][64];  // [k][m]
  __shared__ __align__(16) float Bs[16][64];  // [k][n]
  const int t = threadIdx.x;
  const int m0 = blockIdx.y * 64, n0 = blockIdx.x * 64;
  const int tm = (t >> 4) * 4, tn = (t & 15) * 4;
  const int arow = t >> 2, acol = (t & 3) * 4;
  const int brow = t >> 4, bcol = (t & 15) * 4;
  float acc[4][4] = {};
  for (int k0 = 0; k0 < DMODEL; k0 += 16) {
    const float4 av = *(const float4*)&X[(size_t)(m0 + arow) * DMODEL + k0 + acol];
    const float4 bv = *(const float4*)&W[(size_t)(k0 + brow) * 3072 + n0 + bcol];
    __syncthreads();  // protect previous iteration's reads
    As[acol + 0][arow] = av.x;
    As[acol + 1][arow] = av.y;
    As[acol + 2][arow] = av.z;
    As[acol + 3][arow] = av.w;
    *(float4*)&Bs[brow][bcol] = bv;
    __syncthreads();
#pragma unroll
    for (int kk = 0; kk < 16; ++kk) {
      const float4 a4 = *(const float4*)&As[kk][tm];
      const float4 b4 = *(const float4*)&Bs[kk][tn];
      const float a[4] = {a4.x, a4.y, a4.z, a4.w};
      const float b[4] = {b4.x, b4.y, b4.z, b4.w};
#pragma unroll
      for (int i = 0; i < 4; ++i)
#pragma unroll
        for (int j = 0; j < 4; ++j) acc[i][j] = fmaf(a[i], b[j], acc[i][j]);
    }
  }
#pragma unroll
  for (int i = 0; i < 4; ++i) {
    const int m = m0 + tm + i;
    const int bb = m >> 11, ss = m & 2047;
#pragma unroll
    for (int j = 0; j < 4; ++j) {
      const int n = n0 + tn + j;
      float val = acc[i][j] + bias[n];
      const int which = n >> 10;
      const int d = n & 1023;
      const int h = d >> 6, hd = d & 63;
      const size_t idx = ((size_t)(bb * NH + h) * SEQ + ss) * HD + hd;
      if (which == 0)
        qb[idx] = (__bf16)(val * 0.125f);
      else if (which == 1)
        kb[idx] = (__bf16)val;
      else
        vb[idx] = (__bf16)val;
    }
  }
}

// ---------------------------------------------------------------------------
// K2: fused flash attention. grid = (SEQ/64, BH). 256 thr = 4 waves x 16 q-rows.
// ---------------------------------------------------------------------------
__global__ __launch_bounds__(256) void attn_fused(const __bf16* __restrict__ qb,
                                                  const __bf16* __restrict__ kb,
                                                  const __bf16* __restrict__ vb,
                                                  float* __restrict__ ao) {
  __shared__ __align__(16) __bf16 Vt[64][72];      // V^T tile: [d][kv], padded
  __shared__ __align__(16) __bf16 Ps[4][16][72];   // per-wave P tile [q][kv]
  const int t = threadIdx.x;
  const int lane = t & 63, w = t >> 6;
  const int g = lane >> 4, lr = lane & 15;
  const int bh = blockIdx.y, qt = blockIdx.x;
  const __bf16* Qp = qb + (size_t)bh * SEQ * HD;
  const __bf16* Kp = kb + (size_t)bh * SEQ * HD;
  const __bf16* Vp = vb + (size_t)bh * SEQ * HD;
  const int q0 = qt * 64 + w * 16;

  // Q A-fragments (held all kernel): lane holds Q[q0+lr][g*8..+8] and +32
  const bf16x8 aq0 = *reinterpret_cast<const bf16x8*>(Qp + (size_t)(q0 + lr) * HD + g * 8);
  const bf16x8 aq1 = *reinterpret_cast<const bf16x8*>(Qp + (size_t)(q0 + lr) * HD + 32 + g * 8);

  f32x4 o[4] = {};           // PV accumulators, d-blocks of 16
  float mrun[4], lrun[4];
#pragma unroll
  for (int r = 0; r < 4; ++r) { mrun[r] = -1e30f; lrun[r] = 0.f; }

  const int stV_kv = t >> 2;         // 0..63
  const int stV_d0 = (t & 3) * 16;   // 0,16,32,48

  for (int kv0 = 0; kv0 < SEQ; kv0 += 64) {
    // ---- stage V^T into LDS (transpose on write) ----
    const bf16x8 v0 = *reinterpret_cast<const bf16x8*>(Vp + (size_t)(kv0 + stV_kv) * HD + stV_d0);
    const bf16x8 v1 = *reinterpret_cast<const bf16x8*>(Vp + (size_t)(kv0 + stV_kv) * HD + stV_d0 + 8);
#pragma unroll
    for (int e = 0; e < 8; ++e) {
      Vt[stV_d0 + e][stV_kv] = v0[e];
      Vt[stV_d0 + 8 + e][stV_kv] = v1[e];
    }

    // ---- QK^T: S[16 q][64 kv], K B-frags straight from global (L2-hot) ----
    f32x4 s[4];
#pragma unroll
    for (int cb = 0; cb < 4; ++cb) {
      const bf16x8 bk0 =
          *reinterpret_cast<const bf16x8*>(Kp + (size_t)(kv0 + cb * 16 + lr) * HD + g * 8);
      const bf16x8 bk1 =
          *reinterpret_cast<const bf16x8*>(Kp + (size_t)(kv0 + cb * 16 + lr) * HD + 32 + g * 8);
      f32x4 z = {};
      z = __builtin_amdgcn_mfma_f32_16x16x32_bf16(aq0, bk0, z, 0, 0, 0);
      z = __builtin_amdgcn_mfma_f32_16x16x32_bf16(aq1, bk1, z, 0, 0, 0);
      s[cb] = z;
    }

    // ---- online softmax (C layout: row = g*4+r, col = lr) ----
    float mx[4];
#pragma unroll
    for (int r = 0; r < 4; ++r)
      mx[r] = fmaxf(fmaxf(s[0][r], s[1][r]), fmaxf(s[2][r], s[3][r]));
#pragma unroll
    for (int off = 1; off <= 8; off <<= 1)
#pragma unroll
      for (int r = 0; r < 4; ++r) mx[r] = fmaxf(mx[r], __shfl_xor(mx[r], off, 64));

    float p[4][4];  // [cb][r]
    float corr[4], rsum[4];
#pragma unroll
    for (int r = 0; r < 4; ++r) {
      const float mnew = fmaxf(mrun[r], mx[r]);
      corr[r] = __expf(mrun[r] - mnew);
      mrun[r] = mnew;
      float sum = 0.f;
#pragma unroll
      for (int cb = 0; cb < 4; ++cb) {
        p[cb][r] = __expf(s[cb][r] - mnew);
        sum += p[cb][r];
      }
      rsum[r] = sum;
    }
#pragma unroll
    for (int off = 1; off <= 8; off <<= 1)
#pragma unroll
      for (int r = 0; r < 4; ++r) rsum[r] += __shfl_xor(rsum[r], off, 64);
#pragma unroll
    for (int r = 0; r < 4; ++r) lrun[r] = lrun[r] * corr[r] + rsum[r];
#pragma unroll
    for (int dcb = 0; dcb < 4; ++dcb)
#pragma unroll
      for (int r = 0; r < 4; ++r) o[dcb][r] *= corr[r];

    // ---- P (C layout) -> bf16 -> per-wave LDS -> A-frag layout ----
#pragma unroll
    for (int cb = 0; cb < 4; ++cb)
#pragma unroll
      for (int r = 0; r < 4; ++r) Ps[w][g * 4 + r][cb * 16 + lr] = (__bf16)p[cb][r];

    __syncthreads();  // Vt writes visible to all waves

    const bf16x8 pa0 = *reinterpret_cast<const bf16x8*>(&Ps[w][lr][g * 8]);
    const bf16x8 pa1 = *reinterpret_cast<const bf16x8*>(&Ps[w][lr][32 + g * 8]);
#pragma unroll
    for (int dcb = 0; dcb < 4; ++dcb) {
      const bf16x8 bv0 = *reinterpret_cast<const bf16x8*>(&Vt[dcb * 16 + lr][g * 8]);
      const bf16x8 bv1 = *reinterpret_cast<const bf16x8*>(&Vt[dcb * 16 + lr][32 + g * 8]);
      o[dcb] = __builtin_amdgcn_mfma_f32_16x16x32_bf16(pa0, bv0, o[dcb], 0, 0, 0);
      o[dcb] = __builtin_amdgcn_mfma_f32_16x16x32_bf16(pa1, bv1, o[dcb], 0, 0, 0);
    }
    __syncthreads();  // all Vt reads done before next iteration overwrites
  }

  // ---- epilogue: normalize and store fp32 attn [BH][SEQ][64] ----
  float* aob = ao + (size_t)bh * SEQ * HD;
#pragma unroll
  for (int r = 0; r < 4; ++r) {
    const float inv = 1.0f / lrun[r];
#pragma unroll
    for (int dcb = 0; dcb < 4; ++dcb)
      aob[(size_t)(q0 + g * 4 + r) * HD + dcb * 16 + lr] = o[dcb][r] * inv;
  }
}

// ---------------------------------------------------------------------------
// K3: output projection. attn(remapped)[4096,1024] @ W_out[1024,1024] + b -> out
// ---------------------------------------------------------------------------
__global__ __launch_bounds__(256) void out_gemm(const float* __restrict__ A,
                                                const float* __restrict__ W,
                                                const float* __restrict__ bias,
                                                float* __restrict__ out) {
  __shared__ __align__(16) float As[16][64];
  __shared__ __align__(16) float Bs[16][64];
  const int t = threadIdx.x;
  const int m0 = blockIdx.y * 64, n0 = blockIdx.x * 64;
  const int tm = (t >> 4) * 4, tn = (t & 15) * 4;
  const int arow = t >> 2, acol = (t & 3) * 4;
  const int brow = t >> 4, bcol = (t & 15) * 4;
  const int m = m0 + arow;
  const int bb = m >> 11, ss = m & 2047;
  float acc[4][4] = {};
  for (int k0 = 0; k0 < DMODEL; k0 += 16) {
    const int k = k0 + acol;
    // attn logical [m][k] lives at [bb][k>>6][ss][k&63]
    const float4 av =
        *(const float4*)&A[((size_t)(bb * NH + (k >> 6)) * SEQ + ss) * HD + (k & 63)];
    const float4 bv = *(const float4*)&W[(size_t)(k0 + brow) * DMODEL + n0 + bcol];
    __syncthreads();
    As[acol + 0][arow] = av.x;
    As[acol + 1][arow] = av.y;
    As[acol + 2][arow] = av.z;
    As[acol + 3][arow] = av.w;
    *(float4*)&Bs[brow][bcol] = bv;
    __syncthreads();
#pragma unroll
    for (int kk = 0; kk < 16; ++kk) {
      const float4 a4 = *(const float4*)&As[kk][tm];
      const float4 b4 = *(const float4*)&Bs[kk][tn];
      const float a[4] = {a4.x, a4.y, a4.z, a4.w};
      const float b[4] = {b4.x, b4.y, b4.z, b4.w};
#pragma unroll
      for (int i = 0; i < 4; ++i)
#pragma unroll
        for (int j = 0; j < 4; ++j) acc[i][j] = fmaf(a[i], b[j], acc[i][j]);
    }
  }
#pragma unroll
  for (int i = 0; i < 4; ++i)
#pragma unroll
    for (int j = 0; j < 4; ++j) {
      const int n = n0 + tn + j;
      out[(size_t)(m0 + tm + i) * DMODEL + n] = acc[i][j] + bias[n];
    }
}

// ---------------------------------------------------------------------------
extern "C" void kernel_launch(void* const* d_in, const int* in_sizes, int n_in,
                              void* d_out, int out_size, void* d_ws, size_t ws_size,
                              hipStream_t stream) {
  const float* x = (const float*)d_in[0];
  const float* Wqkv = (const float*)d_in[1];
  const float* bqkv = (const float*)d_in[2];
  const float* Wout = (const float*)d_in[3];
  const float* bout = (const float*)d_in[4];
  float* out = (float*)d_out;

  char* ws = (char*)d_ws;
  __bf16* qb = (__bf16*)(ws);                         // 8 MB
  __bf16* kb = (__bf16*)(ws + (8u << 20));            // 8 MB
  __bf16* vb = (__bf16*)(ws + (16u << 20));           // 8 MB
  float* attn = (float*)(ws + (24u << 20));           // 16 MB fp32

  qkv_gemm<<<dim3(3072 / 64, MTOT / 64), 256, 0, stream>>>(x, Wqkv, bqkv, qb, kb, vb);
  attn_fused<<<dim3(SEQ / 64, BH), 256, 0, stream>>>(qb, kb, vb, attn);
  out_gemm<<<dim3(DMODEL / 64, MTOT / 64), 256, 0, stream>>>(attn, Wout, bout, out);
}

// Round 4
// 306.740 us; speedup vs baseline: 2.2184x; 2.2184x over previous
//
#include <hip/hip_runtime.h>
#include <hip/hip_bf16.h>

#define DMODEL 1024
#define NH 16
#define HD 64
#define SEQ 2048
#define BATCH 2
#define BH (BATCH * NH)     // 32
#define MTOT (BATCH * SEQ)  // 4096

typedef _Float16 f16x8 __attribute__((ext_vector_type(8)));
typedef float f32x4 __attribute__((ext_vector_type(4)));

__device__ __forceinline__ void gload_lds16(const void* g, void* l) {
  __builtin_amdgcn_global_load_lds((const __attribute__((address_space(1))) unsigned*)g,
                                   (__attribute__((address_space(3))) unsigned*)l, 16, 0, 0);
}

// ---------------------------------------------------------------------------
// K0a: fp32 -> fp16 flat convert (x)
// ---------------------------------------------------------------------------
__global__ __launch_bounds__(256) void cvt_f2h(const float* __restrict__ in,
                                               _Float16* __restrict__ out, int n8) {
  const int i = blockIdx.x * 256 + threadIdx.x;
  if (i < n8) {
    const float4 a = ((const float4*)in)[i * 2];
    const float4 b = ((const float4*)in)[i * 2 + 1];
    f16x8 o = {(_Float16)a.x, (_Float16)a.y, (_Float16)a.z, (_Float16)a.w,
               (_Float16)b.x, (_Float16)b.y, (_Float16)b.z, (_Float16)b.w};
    *(f16x8*)&out[(size_t)i * 8] = o;
  }
}

// ---------------------------------------------------------------------------
// K0b: fp32 [K][N] -> fp16 transposed [N][K]
// ---------------------------------------------------------------------------
__global__ __launch_bounds__(256) void cvt_transpose(const float* __restrict__ W,
                                                     _Float16* __restrict__ Wt,
                                                     int N, int K) {
  __shared__ float Ls[64][65];
  const int k0 = blockIdx.y * 64, n0 = blockIdx.x * 64;
  const int t = threadIdx.x;
  const int r = t >> 2, c4 = (t & 3) * 16;
#pragma unroll
  for (int j = 0; j < 4; ++j) {
    const float4 v = *(const float4*)&W[(size_t)(k0 + r) * N + n0 + c4 + j * 4];
    Ls[r][c4 + j * 4 + 0] = v.x;
    Ls[r][c4 + j * 4 + 1] = v.y;
    Ls[r][c4 + j * 4 + 2] = v.z;
    Ls[r][c4 + j * 4 + 3] = v.w;
  }
  __syncthreads();
  f16x8 o0, o1;
#pragma unroll
  for (int j = 0; j < 8; ++j) {
    o0[j] = (_Float16)Ls[c4 + j][r];
    o1[j] = (_Float16)Ls[c4 + 8 + j][r];
  }
  *(f16x8*)&Wt[(size_t)(n0 + r) * K + k0 + c4] = o0;
  *(f16x8*)&Wt[(size_t)(n0 + r) * K + k0 + c4 + 8] = o1;
}

// ---------------------------------------------------------------------------
// K1: QKV projection, fp16 MFMA. Xh[4096,1024] @ Wt[3072,1024]^T + b ->
//     q/k/v fp16 [BH][SEQ][64], q pre-scaled by 0.125.
// 128x128 tile, BK=64, 4 waves, 4x4 16x16 frags/wave (m97 structure).
// ---------------------------------------------------------------------------
__global__ __launch_bounds__(256) void qkv_mm(const _Float16* __restrict__ A,
                                              const _Float16* __restrict__ Bt,
                                              const float* __restrict__ bias,
                                              _Float16* __restrict__ qh,
                                              _Float16* __restrict__ kh,
                                              _Float16* __restrict__ vh) {
  __shared__ __align__(16) _Float16 As[128 * 64];
  __shared__ __align__(16) _Float16 Bs[128 * 64];
  const int t = threadIdx.x;
  const int w = t >> 6, lane = t & 63;
  const int g = lane >> 4, lr = lane & 15;
  const int m0 = blockIdx.y * 128, n0 = blockIdx.x * 128;
  const int wr = w >> 1, wc = w & 1;
  const int srow = (lane >> 3);        // 0..7 within 8-row stripe
  const int col8 = (lane & 7) * 8;     // k octet
  f32x4 acc[4][4] = {};

  for (int k0 = 0; k0 < DMODEL; k0 += 64) {
    __syncthreads();
#pragma unroll
    for (int i = 0; i < 4; ++i) {
      const int row = w * 32 + i * 8 + srow;
      gload_lds16(A + (size_t)(m0 + row) * DMODEL + k0 + col8, &As[(w * 4 + i) * 512]);
      gload_lds16(Bt + (size_t)(n0 + row) * DMODEL + k0 + col8, &Bs[(w * 4 + i) * 512]);
    }
    __syncthreads();
#pragma unroll
    for (int ks = 0; ks < 2; ++ks) {
      f16x8 af[4], bf[4];
#pragma unroll
      for (int mi = 0; mi < 4; ++mi)
        af[mi] = *(const f16x8*)&As[(wr * 64 + mi * 16 + lr) * 64 + ks * 32 + g * 8];
#pragma unroll
      for (int ni = 0; ni < 4; ++ni)
        bf[ni] = *(const f16x8*)&Bs[(wc * 64 + ni * 16 + lr) * 64 + ks * 32 + g * 8];
#pragma unroll
      for (int mi = 0; mi < 4; ++mi)
#pragma unroll
        for (int ni = 0; ni < 4; ++ni)
          acc[mi][ni] = __builtin_amdgcn_mfma_f32_16x16x32_f16(af[mi], bf[ni], acc[mi][ni], 0, 0, 0);
    }
  }

#pragma unroll
  for (int ni = 0; ni < 4; ++ni) {
    const int n = n0 + wc * 64 + ni * 16 + lr;
    const float bn = bias[n];
    const int which = n >> 10, d = n & 1023, h = d >> 6, hd = d & 63;
    _Float16* dst = which == 0 ? qh : which == 1 ? kh : vh;
    const float scale = which == 0 ? 0.125f : 1.0f;
#pragma unroll
    for (int mi = 0; mi < 4; ++mi)
#pragma unroll
      for (int r = 0; r < 4; ++r) {
        const int m = m0 + wr * 64 + mi * 16 + g * 4 + r;
        const int bb = m >> 11, ss = m & 2047;
        dst[((size_t)(bb * NH + h) * SEQ + ss) * HD + hd] =
            (_Float16)((acc[mi][ni][r] + bn) * scale);
      }
  }
}

// ---------------------------------------------------------------------------
// K2: fused flash attention, fp16. grid = (SEQ/64, BH). 4 waves x 16 q-rows.
// ---------------------------------------------------------------------------
__global__ __launch_bounds__(256) void attn_fused(const _Float16* __restrict__ qh,
                                                  const _Float16* __restrict__ kh,
                                                  const _Float16* __restrict__ vh,
                                                  _Float16* __restrict__ ao) {
  __shared__ __align__(16) _Float16 Vt[64][72];
  __shared__ __align__(16) _Float16 Ps[4][16][72];
  const int t = threadIdx.x;
  const int lane = t & 63, w = t >> 6;
  const int g = lane >> 4, lr = lane & 15;
  const int bh = blockIdx.y, qt = blockIdx.x;
  const _Float16* Qp = qh + (size_t)bh * SEQ * HD;
  const _Float16* Kp = kh + (size_t)bh * SEQ * HD;
  const _Float16* Vp = vh + (size_t)bh * SEQ * HD;
  const int q0 = qt * 64 + w * 16;

  const f16x8 aq0 = *reinterpret_cast<const f16x8*>(Qp + (size_t)(q0 + lr) * HD + g * 8);
  const f16x8 aq1 = *reinterpret_cast<const f16x8*>(Qp + (size_t)(q0 + lr) * HD + 32 + g * 8);

  f32x4 o[4] = {};
  float mrun[4], lrun[4];
#pragma unroll
  for (int r = 0; r < 4; ++r) { mrun[r] = -1e30f; lrun[r] = 0.f; }

  const int stV_kv = t >> 2;
  const int stV_d0 = (t & 3) * 16;

  for (int kv0 = 0; kv0 < SEQ; kv0 += 64) {
    const f16x8 v0 = *reinterpret_cast<const f16x8*>(Vp + (size_t)(kv0 + stV_kv) * HD + stV_d0);
    const f16x8 v1 = *reinterpret_cast<const f16x8*>(Vp + (size_t)(kv0 + stV_kv) * HD + stV_d0 + 8);
#pragma unroll
    for (int e = 0; e < 8; ++e) {
      Vt[stV_d0 + e][stV_kv] = v0[e];
      Vt[stV_d0 + 8 + e][stV_kv] = v1[e];
    }

    f32x4 s[4];
#pragma unroll
    for (int cb = 0; cb < 4; ++cb) {
      const f16x8 bk0 =
          *reinterpret_cast<const f16x8*>(Kp + (size_t)(kv0 + cb * 16 + lr) * HD + g * 8);
      const f16x8 bk1 =
          *reinterpret_cast<const f16x8*>(Kp + (size_t)(kv0 + cb * 16 + lr) * HD + 32 + g * 8);
      f32x4 z = {};
      z = __builtin_amdgcn_mfma_f32_16x16x32_f16(aq0, bk0, z, 0, 0, 0);
      z = __builtin_amdgcn_mfma_f32_16x16x32_f16(aq1, bk1, z, 0, 0, 0);
      s[cb] = z;
    }

    float mx[4];
#pragma unroll
    for (int r = 0; r < 4; ++r)
      mx[r] = fmaxf(fmaxf(s[0][r], s[1][r]), fmaxf(s[2][r], s[3][r]));
#pragma unroll
    for (int off = 1; off <= 8; off <<= 1)
#pragma unroll
      for (int r = 0; r < 4; ++r) mx[r] = fmaxf(mx[r], __shfl_xor(mx[r], off, 64));

    float p[4][4];
    float corr[4], rsum[4];
#pragma unroll
    for (int r = 0; r < 4; ++r) {
      const float mnew = fmaxf(mrun[r], mx[r]);
      corr[r] = __expf(mrun[r] - mnew);
      mrun[r] = mnew;
      float sum = 0.f;
#pragma unroll
      for (int cb = 0; cb < 4; ++cb) {
        p[cb][r] = __expf(s[cb][r] - mnew);
        sum += p[cb][r];
      }
      rsum[r] = sum;
    }
#pragma unroll
    for (int off = 1; off <= 8; off <<= 1)
#pragma unroll
      for (int r = 0; r < 4; ++r) rsum[r] += __shfl_xor(rsum[r], off, 64);
#pragma unroll
    for (int r = 0; r < 4; ++r) lrun[r] = lrun[r] * corr[r] + rsum[r];
#pragma unroll
    for (int dcb = 0; dcb < 4; ++dcb)
#pragma unroll
      for (int r = 0; r < 4; ++r) o[dcb][r] *= corr[r];

#pragma unroll
    for (int cb = 0; cb < 4; ++cb)
#pragma unroll
      for (int r = 0; r < 4; ++r) Ps[w][g * 4 + r][cb * 16 + lr] = (_Float16)p[cb][r];

    __syncthreads();

    const f16x8 pa0 = *reinterpret_cast<const f16x8*>(&Ps[w][lr][g * 8]);
    const f16x8 pa1 = *reinterpret_cast<const f16x8*>(&Ps[w][lr][32 + g * 8]);
#pragma unroll
    for (int dcb = 0; dcb < 4; ++dcb) {
      const f16x8 bv0 = *reinterpret_cast<const f16x8*>(&Vt[dcb * 16 + lr][g * 8]);
      const f16x8 bv1 = *reinterpret_cast<const f16x8*>(&Vt[dcb * 16 + lr][32 + g * 8]);
      o[dcb] = __builtin_amdgcn_mfma_f32_16x16x32_f16(pa0, bv0, o[dcb], 0, 0, 0);
      o[dcb] = __builtin_amdgcn_mfma_f32_16x16x32_f16(pa1, bv1, o[dcb], 0, 0, 0);
    }
    __syncthreads();
  }

  _Float16* aob = ao + (size_t)bh * SEQ * HD;
#pragma unroll
  for (int r = 0; r < 4; ++r) {
    const float inv = 1.0f / lrun[r];
#pragma unroll
    for (int dcb = 0; dcb < 4; ++dcb)
      aob[(size_t)(q0 + g * 4 + r) * HD + dcb * 16 + lr] = (_Float16)(o[dcb][r] * inv);
  }
}

// ---------------------------------------------------------------------------
// K3: output projection, fp16 MFMA. attn(remap) @ Wto^T + b -> out fp32
// ---------------------------------------------------------------------------
__global__ __launch_bounds__(256) void out_mm(const _Float16* __restrict__ Ah,
                                              const _Float16* __restrict__ Bt,
                                              const float* __restrict__ bias,
                                              float* __restrict__ out) {
  __shared__ __align__(16) _Float16 As[128 * 64];
  __shared__ __align__(16) _Float16 Bs[128 * 64];
  const int t = threadIdx.x;
  const int w = t >> 6, lane = t & 63;
  const int g = lane >> 4, lr = lane & 15;
  const int m0 = blockIdx.y * 128, n0 = blockIdx.x * 128;
  const int wr = w >> 1, wc = w & 1;
  const int srow = (lane >> 3);
  const int col8 = (lane & 7) * 8;
  f32x4 acc[4][4] = {};

  for (int k0 = 0; k0 < DMODEL; k0 += 64) {
    const int h = k0 >> 6;  // head index for this K-step
    __syncthreads();
#pragma unroll
    for (int i = 0; i < 4; ++i) {
      const int row = w * 32 + i * 8 + srow;
      const int m = m0 + row;
      const int bb = m >> 11, ss = m & 2047;
      gload_lds16(Ah + ((size_t)(bb * NH + h) * SEQ + ss) * HD + col8, &As[(w * 4 + i) * 512]);
      gload_lds16(Bt + (size_t)(n0 + row) * DMODEL + k0 + col8, &Bs[(w * 4 + i) * 512]);
    }
    __syncthreads();
#pragma unroll
    for (int ks = 0; ks < 2; ++ks) {
      f16x8 af[4], bf[4];
#pragma unroll
      for (int mi = 0; mi < 4; ++mi)
        af[mi] = *(const f16x8*)&As[(wr * 64 + mi * 16 + lr) * 64 + ks * 32 + g * 8];
#pragma unroll
      for (int ni = 0; ni < 4; ++ni)
        bf[ni] = *(const f16x8*)&Bs[(wc * 64 + ni * 16 + lr) * 64 + ks * 32 + g * 8];
#pragma unroll
      for (int mi = 0; mi < 4; ++mi)
#pragma unroll
        for (int ni = 0; ni < 4; ++ni)
          acc[mi][ni] = __builtin_amdgcn_mfma_f32_16x16x32_f16(af[mi], bf[ni], acc[mi][ni], 0, 0, 0);
    }
  }

#pragma unroll
  for (int ni = 0; ni < 4; ++ni) {
    const int n = n0 + wc * 64 + ni * 16 + lr;
    const float bn = bias[n];
#pragma unroll
    for (int mi = 0; mi < 4; ++mi)
#pragma unroll
      for (int r = 0; r < 4; ++r) {
        const int m = m0 + wr * 64 + mi * 16 + g * 4 + r;
        out[(size_t)m * DMODEL + n] = acc[mi][ni][r] + bn;
      }
  }
}

// ---------------------------------------------------------------------------
extern "C" void kernel_launch(void* const* d_in, const int* in_sizes, int n_in,
                              void* d_out, int out_size, void* d_ws, size_t ws_size,
                              hipStream_t stream) {
  const float* x = (const float*)d_in[0];
  const float* Wqkv = (const float*)d_in[1];
  const float* bqkv = (const float*)d_in[2];
  const float* Wout = (const float*)d_in[3];
  const float* bout = (const float*)d_in[4];
  float* out = (float*)d_out;

  char* ws = (char*)d_ws;
  const size_t MB = 1u << 20;
  _Float16* Xh = (_Float16*)(ws);                  // 8 MiB [0,8M)
  _Float16* qh = (_Float16*)(ws + 8 * MB);         // 8 MiB
  _Float16* kh = (_Float16*)(ws + 16 * MB);        // 8 MiB
  _Float16* vh = (_Float16*)(ws + 24 * MB);        // 8 MiB
  _Float16* Wtq = (_Float16*)(ws + 32 * MB);       // 6 MiB
  _Float16* Wto = (_Float16*)(ws + 38 * MB + 512 * 1024);  // 2 MiB
  _Float16* attnh = Xh;                            // reuse after qkv_mm

  cvt_f2h<<<dim3(MTOT * DMODEL / 8 / 256), 256, 0, stream>>>(x, Xh, MTOT * DMODEL / 8);
  cvt_transpose<<<dim3(3072 / 64, DMODEL / 64), 256, 0, stream>>>(Wqkv, Wtq, 3072, DMODEL);
  cvt_transpose<<<dim3(DMODEL / 64, DMODEL / 64), 256, 0, stream>>>(Wout, Wto, DMODEL, DMODEL);
  qkv_mm<<<dim3(3072 / 128, MTOT / 128), 256, 0, stream>>>(Xh, Wtq, bqkv, qh, kh, vh);
  attn_fused<<<dim3(SEQ / 64, BH), 256, 0, stream>>>(qh, kh, vh, attnh);
  out_mm<<<dim3(DMODEL / 128, MTOT / 128), 256, 0, stream>>>(attnh, Wto, bout, out);
}

// Round 5
// 253.879 us; speedup vs baseline: 2.6803x; 1.2082x over previous
//
#include <hip/hip_runtime.h>
#include <hip/hip_bf16.h>

#define DMODEL 1024
#define NH 16
#define HD 64
#define SEQ 2048
#define BATCH 2
#define BH (BATCH * NH)     // 32
#define MTOT (BATCH * SEQ)  // 4096

typedef _Float16 f16x8 __attribute__((ext_vector_type(8)));
typedef _Float16 f16x4 __attribute__((ext_vector_type(4)));
typedef _Float16 f16x2 __attribute__((ext_vector_type(2)));
typedef float f32x4 __attribute__((ext_vector_type(4)));
typedef float f32x16 __attribute__((ext_vector_type(16)));

__device__ __forceinline__ void gload_lds16(const void* g, void* l) {
  __builtin_amdgcn_global_load_lds((const __attribute__((address_space(1))) unsigned*)g,
                                   (__attribute__((address_space(3))) unsigned*)l, 16, 0, 0);
}

// ---------------------------------------------------------------------------
// K0a: fp32 -> fp16 flat convert (x)
// ---------------------------------------------------------------------------
__global__ __launch_bounds__(256) void cvt_f2h(const float* __restrict__ in,
                                               _Float16* __restrict__ out, int n8) {
  const int i = blockIdx.x * 256 + threadIdx.x;
  if (i < n8) {
    const float4 a = ((const float4*)in)[i * 2];
    const float4 b = ((const float4*)in)[i * 2 + 1];
    f16x8 o = {(_Float16)a.x, (_Float16)a.y, (_Float16)a.z, (_Float16)a.w,
               (_Float16)b.x, (_Float16)b.y, (_Float16)b.z, (_Float16)b.w};
    *(f16x8*)&out[(size_t)i * 8] = o;
  }
}

// ---------------------------------------------------------------------------
// K0b: fp32 [K][N] -> fp16 transposed [N][K]
// ---------------------------------------------------------------------------
__global__ __launch_bounds__(256) void cvt_transpose(const float* __restrict__ W,
                                                     _Float16* __restrict__ Wt,
                                                     int N, int K) {
  __shared__ float Ls[64][65];
  const int k0 = blockIdx.y * 64, n0 = blockIdx.x * 64;
  const int t = threadIdx.x;
  const int r = t >> 2, c4 = (t & 3) * 16;
#pragma unroll
  for (int j = 0; j < 4; ++j) {
    const float4 v = *(const float4*)&W[(size_t)(k0 + r) * N + n0 + c4 + j * 4];
    Ls[r][c4 + j * 4 + 0] = v.x;
    Ls[r][c4 + j * 4 + 1] = v.y;
    Ls[r][c4 + j * 4 + 2] = v.z;
    Ls[r][c4 + j * 4 + 3] = v.w;
  }
  __syncthreads();
  f16x8 o0, o1;
#pragma unroll
  for (int j = 0; j < 8; ++j) {
    o0[j] = (_Float16)Ls[c4 + j][r];
    o1[j] = (_Float16)Ls[c4 + 8 + j][r];
  }
  *(f16x8*)&Wt[(size_t)(n0 + r) * K + k0 + c4] = o0;
  *(f16x8*)&Wt[(size_t)(n0 + r) * K + k0 + c4 + 8] = o1;
}

// ---------------------------------------------------------------------------
// K1: QKV projection, fp16 MFMA (m97 structure, 128x128 tile, BK=64).
// ---------------------------------------------------------------------------
__global__ __launch_bounds__(256) void qkv_mm(const _Float16* __restrict__ A,
                                              const _Float16* __restrict__ Bt,
                                              const float* __restrict__ bias,
                                              _Float16* __restrict__ qh,
                                              _Float16* __restrict__ kh,
                                              _Float16* __restrict__ vh) {
  __shared__ __align__(16) _Float16 As[128 * 64];
  __shared__ __align__(16) _Float16 Bs[128 * 64];
  const int t = threadIdx.x;
  const int w = t >> 6, lane = t & 63;
  const int g = lane >> 4, lr = lane & 15;
  const int m0 = blockIdx.y * 128, n0 = blockIdx.x * 128;
  const int wr = w >> 1, wc = w & 1;
  const int srow = (lane >> 3);
  const int col8 = (lane & 7) * 8;
  f32x4 acc[4][4] = {};

  for (int k0 = 0; k0 < DMODEL; k0 += 64) {
    __syncthreads();
#pragma unroll
    for (int i = 0; i < 4; ++i) {
      const int row = w * 32 + i * 8 + srow;
      gload_lds16(A + (size_t)(m0 + row) * DMODEL + k0 + col8, &As[(w * 4 + i) * 512]);
      gload_lds16(Bt + (size_t)(n0 + row) * DMODEL + k0 + col8, &Bs[(w * 4 + i) * 512]);
    }
    __syncthreads();
#pragma unroll
    for (int ks = 0; ks < 2; ++ks) {
      f16x8 af[4], bf[4];
#pragma unroll
      for (int mi = 0; mi < 4; ++mi)
        af[mi] = *(const f16x8*)&As[(wr * 64 + mi * 16 + lr) * 64 + ks * 32 + g * 8];
#pragma unroll
      for (int ni = 0; ni < 4; ++ni)
        bf[ni] = *(const f16x8*)&Bs[(wc * 64 + ni * 16 + lr) * 64 + ks * 32 + g * 8];
#pragma unroll
      for (int mi = 0; mi < 4; ++mi)
#pragma unroll
        for (int ni = 0; ni < 4; ++ni)
          acc[mi][ni] = __builtin_amdgcn_mfma_f32_16x16x32_f16(af[mi], bf[ni], acc[mi][ni], 0, 0, 0);
    }
  }

#pragma unroll
  for (int ni = 0; ni < 4; ++ni) {
    const int n = n0 + wc * 64 + ni * 16 + lr;
    const float bn = bias[n];
    const int which = n >> 10, d = n & 1023, h = d >> 6, hd = d & 63;
    _Float16* dst = which == 0 ? qh : which == 1 ? kh : vh;
    const float scale = which == 0 ? 0.125f : 1.0f;
#pragma unroll
    for (int mi = 0; mi < 4; ++mi)
#pragma unroll
      for (int r = 0; r < 4; ++r) {
        const int m = m0 + wr * 64 + mi * 16 + g * 4 + r;
        const int bb = m >> 11, ss = m & 2047;
        dst[((size_t)(bb * NH + h) * SEQ + ss) * HD + hd] =
            (_Float16)((acc[mi][ni][r] + bn) * scale);
      }
  }
}

// ---------------------------------------------------------------------------
// K2: fused flash attention, swapped-QK^T 32x32 structure.
// grid = (SEQ/128, BH), 256 thr = 4 waves x 32 q-rows. KVBLK = 64.
// Each lane owns one q row (q = lane&31); S^T/O^T keep q lane-local.
// ---------------------------------------------------------------------------
__global__ __launch_bounds__(256, 2) void attn_fused(const _Float16* __restrict__ qh,
                                                     const _Float16* __restrict__ kh,
                                                     const _Float16* __restrict__ vh,
                                                     _Float16* __restrict__ ao) {
  __shared__ __align__(16) _Float16 Vt[64][76];  // V^T tile [d][kv], stride 76 (2-way free)
  const int t = threadIdx.x;
  const int lane = t & 63, w = t >> 6;
  const int q = lane & 31, hi = lane >> 5;
  const int bh = blockIdx.y;
  const int q0 = blockIdx.x * 128 + w * 32;
  const _Float16* Qp = qh + (size_t)bh * SEQ * HD;
  const _Float16* Kp = kh + (size_t)bh * SEQ * HD;
  const _Float16* Vp = vh + (size_t)bh * SEQ * HD;

  // Q as B-operand frags: Q^T[k][q] -> lane holds Q[q0+q][ks*16 + hi*8 .. +8]
  f16x8 qf[4];
#pragma unroll
  for (int ks = 0; ks < 4; ++ks)
    qf[ks] = *(const f16x8*)(Qp + (size_t)(q0 + q) * HD + ks * 16 + hi * 8);

  f32x16 o0 = {}, o1 = {};  // O^T accum, d-blocks 0/1: d = 32*db + (r&3) + 8*(r>>2) + 4*hi
  float mrun = -3e30f, lrun = 0.f;

  const int skv = t & 63;        // staging: kv row
  const int sq4 = t >> 6;        // staging: d quarter (== wave id)

  for (int kv0 = 0; kv0 < SEQ; kv0 += 64) {
    // ---- issue V loads early; sync; transpose-write V^T into LDS ----
    const f16x8 sv0 = *(const f16x8*)(Vp + (size_t)(kv0 + skv) * HD + sq4 * 16);
    const f16x8 sv1 = *(const f16x8*)(Vp + (size_t)(kv0 + skv) * HD + sq4 * 16 + 8);
    __syncthreads();  // previous tile's Vt reads complete
#pragma unroll
    for (int e = 0; e < 8; ++e) {
      Vt[sq4 * 16 + e][skv] = sv0[e];
      Vt[sq4 * 16 + 8 + e][skv] = sv1[e];
    }

    // ---- QK^T (swapped): S^T[kv][q] = K . Q^T ; K read direct from global ----
    f32x16 s0 = {}, s1 = {};
#pragma unroll
    for (int ks = 0; ks < 4; ++ks) {
      const f16x8 k0 = *(const f16x8*)(Kp + (size_t)(kv0 + q) * HD + ks * 16 + hi * 8);
      const f16x8 k1 = *(const f16x8*)(Kp + (size_t)(kv0 + 32 + q) * HD + ks * 16 + hi * 8);
      s0 = __builtin_amdgcn_mfma_f32_32x32x16_f16(k0, qf[ks], s0, 0, 0, 0);
      s1 = __builtin_amdgcn_mfma_f32_32x32x16_f16(k1, qf[ks], s1, 0, 0, 0);
    }

    // ---- online softmax: lane owns row q; 32 values here + 32 in lane^32 ----
    float tm[16];
#pragma unroll
    for (int r = 0; r < 16; ++r) tm[r] = fmaxf(s0[r], s1[r]);
#pragma unroll
    for (int d = 8; d > 0; d >>= 1)
#pragma unroll
      for (int r = 0; r < d; ++r) tm[r] = fmaxf(tm[r], tm[r + d]);
    float mx = fmaxf(tm[0], __shfl_xor(tm[0], 32));
    const float mnew = fmaxf(mrun, mx);
    const float corr = __expf(mrun - mnew);
    mrun = mnew;
#pragma unroll
    for (int r = 0; r < 16; ++r) {
      s0[r] = __expf(s0[r] - mnew);
      s1[r] = __expf(s1[r] - mnew);
    }
    float ts[16];
#pragma unroll
    for (int r = 0; r < 16; ++r) ts[r] = s0[r] + s1[r];
#pragma unroll
    for (int d = 8; d > 0; d >>= 1)
#pragma unroll
      for (int r = 0; r < d; ++r) ts[r] += ts[r + d];
    float rs = ts[0] + __shfl_xor(ts[0], 32);
    lrun = lrun * corr + rs;
#pragma unroll
    for (int r = 0; r < 16; ++r) {
      o0[r] *= corr;
      o1[r] *= corr;
    }

    __syncthreads();  // Vt writes visible

    // ---- PV: O^T += V^T . P^T. Build P^T B-frags in-register. ----
    // p-index map: p[16c + 4m + s] = P[q][kv = 32c + 8m + 4hi + s]  (c: s0/s1)
#pragma unroll
    for (int ks = 0; ks < 4; ++ks) {
      const int base = 8 * (ks & 1);
      unsigned u0, u1, u2, u3;
#pragma unroll
      for (int w01 = 0; w01 < 2; ++w01) {
        float a0, a1, b0, b1;
        if (ks < 2) {
          a0 = s0[base + 2 * w01];     a1 = s0[base + 2 * w01 + 1];
          b0 = s0[base + 4 + 2 * w01]; b1 = s0[base + 4 + 2 * w01 + 1];
        } else {
          a0 = s1[base + 2 * w01];     a1 = s1[base + 2 * w01 + 1];
          b0 = s1[base + 4 + 2 * w01]; b1 = s1[base + 4 + 2 * w01 + 1];
        }
        f16x2 hm0; hm0[0] = (_Float16)a0; hm0[1] = (_Float16)a1;  // m = mb
        f16x2 hm1; hm1[0] = (_Float16)b0; hm1[1] = (_Float16)b1;  // m = mb+1
        unsigned Pm0, Pm1;
        __builtin_memcpy(&Pm0, &hm0, 4);
        __builtin_memcpy(&Pm1, &hm1, 4);
        const unsigned local = hi ? Pm1 : Pm0;  // m = mb + hi (own half)
        const unsigned sent = hi ? Pm0 : Pm1;   // m = mb + (hi^1) (for partner)
        const unsigned cross = __shfl_xor(sent, 32);
        const unsigned wa = hi ? cross : local;  // word for src-half 0
        const unsigned wb = hi ? local : cross;  // word for src-half 1
        if (w01 == 0) { u0 = wa; u2 = wb; } else { u1 = wa; u3 = wb; }
      }
      unsigned ww[4] = {u0, u1, u2, u3};
      f16x8 pb;
      __builtin_memcpy(&pb, ww, 16);
      const f16x8 va0 = *(const f16x8*)&Vt[0 + q][ks * 16 + hi * 8];
      const f16x8 va1 = *(const f16x8*)&Vt[32 + q][ks * 16 + hi * 8];
      o0 = __builtin_amdgcn_mfma_f32_32x32x16_f16(va0, pb, o0, 0, 0, 0);
      o1 = __builtin_amdgcn_mfma_f32_32x32x16_f16(va1, pb, o1, 0, 0, 0);
    }
  }

  // ---- epilogue: O[q][d] = O^T[d][q] / l ; pack 4 consecutive d per store ----
  const float invl = 1.0f / lrun;
  _Float16* aob = ao + (size_t)bh * SEQ * HD + (size_t)(q0 + q) * HD;
#pragma unroll
  for (int m = 0; m < 4; ++m) {
    f16x4 v0, v1;
#pragma unroll
    for (int s2 = 0; s2 < 4; ++s2) {
      v0[s2] = (_Float16)(o0[4 * m + s2] * invl);
      v1[s2] = (_Float16)(o1[4 * m + s2] * invl);
    }
    *(f16x4*)(aob + 8 * m + 4 * hi) = v0;
    *(f16x4*)(aob + 32 + 8 * m + 4 * hi) = v1;
  }
}

// ---------------------------------------------------------------------------
// K3: output projection, fp16 MFMA.
// ---------------------------------------------------------------------------
__global__ __launch_bounds__(256) void out_mm(const _Float16* __restrict__ Ah,
                                              const _Float16* __restrict__ Bt,
                                              const float* __restrict__ bias,
                                              float* __restrict__ out) {
  __shared__ __align__(16) _Float16 As[128 * 64];
  __shared__ __align__(16) _Float16 Bs[128 * 64];
  const int t = threadIdx.x;
  const int w = t >> 6, lane = t & 63;
  const int g = lane >> 4, lr = lane & 15;
  const int m0 = blockIdx.y * 128, n0 = blockIdx.x * 128;
  const int wr = w >> 1, wc = w & 1;
  const int srow = (lane >> 3);
  const int col8 = (lane & 7) * 8;
  f32x4 acc[4][4] = {};

  for (int k0 = 0; k0 < DMODEL; k0 += 64) {
    const int h = k0 >> 6;
    __syncthreads();
#pragma unroll
    for (int i = 0; i < 4; ++i) {
      const int row = w * 32 + i * 8 + srow;
      const int m = m0 + row;
      const int bb = m >> 11, ss = m & 2047;
      gload_lds16(Ah + ((size_t)(bb * NH + h) * SEQ + ss) * HD + col8, &As[(w * 4 + i) * 512]);
      gload_lds16(Bt + (size_t)(n0 + row) * DMODEL + k0 + col8, &Bs[(w * 4 + i) * 512]);
    }
    __syncthreads();
#pragma unroll
    for (int ks = 0; ks < 2; ++ks) {
      f16x8 af[4], bf[4];
#pragma unroll
      for (int mi = 0; mi < 4; ++mi)
        af[mi] = *(const f16x8*)&As[(wr * 64 + mi * 16 + lr) * 64 + ks * 32 + g * 8];
#pragma unroll
      for (int ni = 0; ni < 4; ++ni)
        bf[ni] = *(const f16x8*)&Bs[(wc * 64 + ni * 16 + lr) * 64 + ks * 32 + g * 8];
#pragma unroll
      for (int mi = 0; mi < 4; ++mi)
#pragma unroll
        for (int ni = 0; ni < 4; ++ni)
          acc[mi][ni] = __builtin_amdgcn_mfma_f32_16x16x32_f16(af[mi], bf[ni], acc[mi][ni], 0, 0, 0);
    }
  }

#pragma unroll
  for (int ni = 0; ni < 4; ++ni) {
    const int n = n0 + wc * 64 + ni * 16 + lr;
    const float bn = bias[n];
#pragma unroll
    for (int mi = 0; mi < 4; ++mi)
#pragma unroll
      for (int r = 0; r < 4; ++r) {
        const int m = m0 + wr * 64 + mi * 16 + g * 4 + r;
        out[(size_t)m * DMODEL + n] = acc[mi][ni][r] + bn;
      }
  }
}

// ---------------------------------------------------------------------------
extern "C" void kernel_launch(void* const* d_in, const int* in_sizes, int n_in,
                              void* d_out, int out_size, void* d_ws, size_t ws_size,
                              hipStream_t stream) {
  const float* x = (const float*)d_in[0];
  const float* Wqkv = (const float*)d_in[1];
  const float* bqkv = (const float*)d_in[2];
  const float* Wout = (const float*)d_in[3];
  const float* bout = (const float*)d_in[4];
  float* out = (float*)d_out;

  char* ws = (char*)d_ws;
  const size_t MB = 1u << 20;
  _Float16* Xh = (_Float16*)(ws);                          // 8 MiB
  _Float16* qh = (_Float16*)(ws + 8 * MB);                 // 8 MiB
  _Float16* kh = (_Float16*)(ws + 16 * MB);                // 8 MiB
  _Float16* vh = (_Float16*)(ws + 24 * MB);                // 8 MiB
  _Float16* Wtq = (_Float16*)(ws + 32 * MB);               // 6 MiB
  _Float16* Wto = (_Float16*)(ws + 38 * MB + 512 * 1024);  // 2 MiB
  _Float16* attnh = Xh;                                    // reuse after qkv_mm

  cvt_f2h<<<dim3(MTOT * DMODEL / 8 / 256), 256, 0, stream>>>(x, Xh, MTOT * DMODEL / 8);
  cvt_transpose<<<dim3(3072 / 64, DMODEL / 64), 256, 0, stream>>>(Wqkv, Wtq, 3072, DMODEL);
  cvt_transpose<<<dim3(DMODEL / 64, DMODEL / 64), 256, 0, stream>>>(Wout, Wto, DMODEL, DMODEL);
  qkv_mm<<<dim3(3072 / 128, MTOT / 128), 256, 0, stream>>>(Xh, Wtq, bqkv, qh, kh, vh);
  attn_fused<<<dim3(SEQ / 128, BH), 256, 0, stream>>>(qh, kh, vh, attnh);
  out_mm<<<dim3(DMODEL / 128, MTOT / 128), 256, 0, stream>>>(attnh, Wto, bout, out);
}